// Round 6
// baseline (35.272 us; speedup 1.0000x reference)
//
#include <hip/hip_runtime.h>
#include <math.h>

#define TOPM 128   // top-M node ids served by the dense table

// ---- DPP wave reductions: VALU pipe only ----
template<int CTRL, int ROW_MASK>
__device__ __forceinline__ float dpp_add(float v) {
    const int s = __builtin_amdgcn_update_dpp(0, __float_as_int(v), CTRL, ROW_MASK, 0xf, false);
    return v + __int_as_float(s);
}
template<int CTRL, int ROW_MASK>
__device__ __forceinline__ float dpp_mul(float v) {
    const int s = __builtin_amdgcn_update_dpp(0x3f800000, __float_as_int(v), CTRL, ROW_MASK, 0xf, false);
    return v * __int_as_float(s);
}
__device__ __forceinline__ float wave_sum63(float v) {   // total in lane 63
    v = dpp_add<0x111, 0xf>(v);  // row_shr:1
    v = dpp_add<0x112, 0xf>(v);  // row_shr:2
    v = dpp_add<0x114, 0xf>(v);  // row_shr:4
    v = dpp_add<0x118, 0xf>(v);  // row_shr:8
    v = dpp_add<0x142, 0xa>(v);  // row_bcast:15
    v = dpp_add<0x143, 0xc>(v);  // row_bcast:31
    return v;
}
__device__ __forceinline__ float wave_prod63(float v) {  // product in lane 63
    v = dpp_mul<0x111, 0xf>(v);
    v = dpp_mul<0x112, 0xf>(v);
    v = dpp_mul<0x114, 0xf>(v);
    v = dpp_mul<0x118, 0xf>(v);
    v = dpp_mul<0x142, 0xa>(v);
    v = dpp_mul<0x143, 0xc>(v);
    return v;
}
__device__ __forceinline__ float readlane_f(float v, int l) {
    return __int_as_float(__builtin_amdgcn_readlane(__float_as_int(v), l));
}
__device__ __forceinline__ float dot8(float4 a, float4 b, float4 c, float4 d) {
    return a.x*b.x + a.y*b.y + a.z*b.z + a.w*b.w
         + c.x*d.x + c.y*d.y + c.z*d.z + c.w*d.w;
}

// Kernel 1: Ytop[b][j] = x[b] . W[N-TOPM+j] + bias[N-TOPM+j]
// Wave per (16-b chunk, 8-node group); W rows held in registers (reuse x16).
__global__ __launch_bounds__(256)
void dense_top(const float* __restrict__ x, const float* __restrict__ W,
               const float* __restrict__ bias, float* __restrict__ ytop, int N)
{
    const int lane = threadIdx.x & 63;
    const int wi = blockIdx.x * 4 + (threadIdx.x >> 6);
    const int bchunk = wi >> 4;
    const int jg = wi & 15;
    const int tb = N - TOPM;

    float4 wa[8], wb[8];
    #pragma unroll
    for (int r = 0; r < 8; ++r) {
        const float4* wr = reinterpret_cast<const float4*>(W + (size_t)(tb + jg*8 + r) * 512);
        wa[r] = wr[lane]; wb[r] = wr[lane + 64];
    }
    float bb[8];
    #pragma unroll
    for (int r = 0; r < 8; ++r) bb[r] = bias[tb + jg*8 + r];

    for (int bl = 0; bl < 16; ++bl) {
        const int b = bchunk * 16 + bl;
        const float4* xr = reinterpret_cast<const float4*>(x + (size_t)b * 512);
        const float4 xa = xr[lane], xb = xr[lane + 64];
        float acc[8];
        #pragma unroll
        for (int r = 0; r < 8; ++r) acc[r] = dot8(xa, wa[r], xb, wb[r]);
        #pragma unroll
        for (int r = 0; r < 8; ++r) acc[r] = wave_sum63(acc[r]);
        float tv = 0.0f;
        #pragma unroll
        for (int r = 0; r < 8; ++r) {
            const float tot = readlane_f(acc[r], 63) + bb[r];
            tv = (lane == r) ? tot : tv;
        }
        if (lane < 8) ytop[(size_t)b * TOPM + jg * 8 + lane] = tv;
    }
}

// Kernel 2: wave per (b,r) pair. Path entries with node id >= N-TOPM come from
// the table (any depth — test is on the id, so correct for any distribution);
// entries 7..15 are gathered unconditionally (gather is always correct).
// Fast path requires entries 0..6 to be table-served; else guarded slow path.
__global__ __launch_bounds__(256)
void huff_table(const float* __restrict__ x, const int* __restrict__ tgt,
                const float* __restrict__ W, const float* __restrict__ bias,
                const int* __restrict__ paths, const float* __restrict__ codes,
                const float* __restrict__ ytop, float* __restrict__ out,
                int R, int N)
{
    const int lane = threadIdx.x & 63;
    const int p = blockIdx.x * 4 + (threadIdx.x >> 6);
    const int b = p / R;
    const int tb = N - TOPM;

    const float4* xr = reinterpret_cast<const float4*>(x + (size_t)b * 512);
    const float4 xa = xr[lane], xb = xr[lane + 64];

    const int c = tgt[p];
    const int dd = (lane < 16) ? lane : 15;
    const int   nd = paths[(size_t)c * 16 + dd];
    const float cd = codes[(size_t)c * 16 + dd];
    const float sd = 1.0f - 2.0f * cd;
    const float bv = bias[nd];

    const unsigned long long gmask = __ballot(lane < 16 && nd < tb);

    if ((gmask & 0x7Full) == 0) {
        // d=0..6 from table
        float tval = 0.0f;
        if (lane < 7) tval = ytop[(size_t)b * TOPM + (nd - tb)];

        // d=7..15 gathered, all loads batched for MLP
        float4 wA[9], wB[9];
        #pragma unroll
        for (int i = 0; i < 9; ++i) {
            const int snid = __builtin_amdgcn_readlane(nd, 7 + i);
            const float4* wr = reinterpret_cast<const float4*>(W + (size_t)snid * 512);
            wA[i] = wr[lane]; wB[i] = wr[lane + 64];
        }
        float acc[9];
        #pragma unroll
        for (int i = 0; i < 9; ++i) acc[i] = dot8(xa, wA[i], xb, wB[i]);
        #pragma unroll
        for (int i = 0; i < 9; ++i) acc[i] = wave_sum63(acc[i]);

        float f = 1.0f;                       // per-lane table factors
        if (lane < 7) f = 1.0f + __expf(-sd * tval);
        f = wave_prod63(f);
        float q = readlane_f(f, 63);

        #pragma unroll
        for (int i = 0; i < 9; ++i) {
            const float tot = readlane_f(acc[i], 63) + readlane_f(bv, 7 + i);
            const float ss  = readlane_f(sd, 7 + i);
            q *= 1.0f + __expf(-ss * tot);    // prod sigmoid = 1/prod(1+exp(-s*t))
        }
        if (lane == 0) out[p] = 1.0f / q;
    } else {
        // generic slow path (not expected to run): serial per-entry
        float q = 1.0f;
        for (int d = 0; d < 16; ++d) {
            const int snid = __builtin_amdgcn_readlane(nd, d);
            const float ss = readlane_f(sd, d);
            float t;
            if (snid >= tb) {
                t = ytop[(size_t)b * TOPM + (snid - tb)];
            } else {
                const float4* wr = reinterpret_cast<const float4*>(W + (size_t)snid * 512);
                const float4 wva = wr[lane], wvb = wr[lane + 64];
                float a = dot8(xa, wva, xb, wvb);
                a = wave_sum63(a);
                t = readlane_f(a, 63) + readlane_f(bv, d);
            }
            q *= 1.0f + __expf(-ss * t);
        }
        if (lane == 0) out[p] = 1.0f / q;
    }
}

// Generic fallback for unexpected shapes.
__global__ __launch_bounds__(256)
void huff_kernel_gen(const float* __restrict__ x, const int* __restrict__ tgt,
                     const float* __restrict__ W, const float* __restrict__ bias,
                     const int* __restrict__ paths, const float* __restrict__ codes,
                     float* __restrict__ out, int R, int I, int D, int npairs)
{
    const int lane = threadIdx.x & 63;
    const int p = blockIdx.x * 4 + (threadIdx.x >> 6);
    if (p >= npairs) return;
    const int b = p / R;
    const float4* xrow = reinterpret_cast<const float4*>(x + (size_t)b * I);
    const float4 xa = xrow[lane];
    const float4 xb = xrow[lane + 64];
    const int c = tgt[p];
    float q = 1.0f;
    for (int d = 0; d < D; ++d) {
        const int node = paths[(size_t)c * D + d];
        const float4* wr = reinterpret_cast<const float4*>(W + (size_t)node * I);
        const float4 wa = wr[lane];
        const float4 wb = wr[lane + 64];
        float acc = dot8(xa, wa, xb, wb);
        #pragma unroll
        for (int off = 32; off; off >>= 1) acc += __shfl_xor(acc, off, 64);
        const float t = acc + bias[node];
        const float s = 1.0f - 2.0f * codes[(size_t)c * D + d];
        q *= 1.0f + __expf(-s * t);
    }
    if (lane == 0) out[p] = 1.0f / q;
}

extern "C" void kernel_launch(void* const* d_in, const int* in_sizes, int n_in,
                              void* d_out, int out_size, void* d_ws, size_t ws_size,
                              hipStream_t stream) {
    const float* x     = (const float*)d_in[0];
    const int*   tgt   = (const int*)  d_in[1];
    const float* W     = (const float*)d_in[2];
    const float* bias  = (const float*)d_in[3];
    const int*   paths = (const int*)  d_in[4];
    const float* codes = (const float*)d_in[5];
    float* out = (float*)d_out;

    const int N = in_sizes[3];            // total_nodes = nb_classes - 1
    const int C = N + 1;                  // nb_classes
    const int I = in_sizes[2] / N;        // input dim (512)
    const int B = in_sizes[0] / I;        // batch (1024)
    const int R = in_sizes[1] / B;        // requests (8)
    const int D = in_sizes[4] / C;        // max path depth

    const int npairs = B * R;
    const size_t ws_need = (size_t)B * TOPM * sizeof(float);

    if (D == 16 && I == 512 && (B % 16) == 0 && (npairs % 4) == 0 &&
        N > TOPM && ws_size >= ws_need) {
        float* ytop = (float*)d_ws;
        dense_top<<<B / 4, 256, 0, stream>>>(x, W, bias, ytop, N);
        huff_table<<<npairs / 4, 256, 0, stream>>>(x, tgt, W, bias, paths, codes,
                                                   ytop, out, R, N);
    } else {
        const int grid = (npairs + 3) / 4;
        huff_kernel_gen<<<grid, 256, 0, stream>>>(x, tgt, W, bias, paths, codes,
                                                  out, R, I, D, npairs);
    }
}